// Round 10
// baseline (331.535 us; speedup 1.0000x reference)
//
#include <hip/hip_runtime.h>
#include <hip/hip_bf16.h>

#define B_ 32
#define D_ 512
#define N_ 1024
#define M_ 1024
#define BM 128
#define BK 64
#define NSTEP (D_ / BK)   // 8

typedef __attribute__((ext_vector_type(8))) short bf16x8;
typedef __attribute__((ext_vector_type(4))) short s16x4;
typedef __attribute__((ext_vector_type(4))) float f32x4;
typedef __attribute__((ext_vector_type(4))) int   i32x4;
typedef unsigned short ushort_t;

__device__ __forceinline__ unsigned map_f(float f) {
    unsigned b = __float_as_uint(f);
    return (b & 0x80000000u) ? ~b : (b | 0x80000000u);
}

// ============================================================================
// Fused fp32->bf16 GEMM-max. SINGLE-buffered LDS (33KB -> 4 blocks/CU).
// R8's verified layout: LDS tile [k=64][j=128] bf16, row 256B = 16 granules;
// granule gr of row k at byte k*256 + 16*(gr ^ (2*(k&3))).  b128 writes
// (R8-verified), ds_read_b64_tr_b16 fragment reads (R5-verified correct).
// ============================================================================
struct __align__(16) GSmem {
    ushort_t As[BM * BK];   // 16 KB  @ 0
    ushort_t Bs[BM * BK];   // 16 KB  @ 16384
    float red[4];
};

// Load this thread's 4 granules (= 8 float4) of a [64][128] fp32 tile slice.
// krb = wave*16 + (lane>>4)*4 ; gr = lane&15. Per it: 16 lanes cover one full
// 512B row contiguously (two interleaved dwordx4 instrs).
__device__ __forceinline__ void load_tile(const float* __restrict__ p, int k0,
                                          int krb, int gr, float4* fl) {
    #pragma unroll
    for (int it = 0; it < 4; ++it) {
        const float* q = p + (size_t)(k0 + krb + it) * N_ + gr * 8;
        fl[2 * it]     = *reinterpret_cast<const float4*>(q);
        fl[2 * it + 1] = *reinterpret_cast<const float4*>(q + 4);
    }
}

// Convert + write this thread's 4 granules into one LDS tile (swizzled, b128).
__device__ __forceinline__ void flush_tile(char* lds, int krb, int gr, const float4* fl) {
    #pragma unroll
    for (int it = 0; it < 4; ++it) {
        const int k = krb + it;
        const float4& f0 = fl[2 * it];
        const float4& f1 = fl[2 * it + 1];
        __hip_bfloat162 h0 = __float22bfloat162_rn(make_float2(f0.x, f0.y));
        __hip_bfloat162 h1 = __float22bfloat162_rn(make_float2(f0.z, f0.w));
        __hip_bfloat162 h2 = __float22bfloat162_rn(make_float2(f1.x, f1.y));
        __hip_bfloat162 h3 = __float22bfloat162_rn(make_float2(f1.z, f1.w));
        i32x4 v = { *reinterpret_cast<const int*>(&h0), *reinterpret_cast<const int*>(&h1),
                    *reinterpret_cast<const int*>(&h2), *reinterpret_cast<const int*>(&h3) };
        *reinterpret_cast<i32x4*>(lds + k * 256 + 16 * (gr ^ (2 * (k & 3)))) = v;
    }
}

__global__ __launch_bounds__(256, 4)
void fused_gemm_max_kernel(const float* __restrict__ e1, const float* __restrict__ e2,
                           float* __restrict__ out) {
    __shared__ GSmem sm;
    const int wg  = blockIdx.x;
    const int swz = (wg & 7) * 256 + (wg >> 3);   // XCD swizzle (2048 % 8 == 0)
    const int b    = swz >> 6;
    const int tile = swz & 63;
    const int tn = (tile >> 3) * BM;
    const int tc = (tile & 7) * BM;

    const int t    = threadIdx.x;
    const int lane = t & 63;
    const int wave = t >> 6;
    const int wr   = (wave >> 1) * 64;   // A j-quadrant
    const int wc   = (wave & 1) * 64;    // B j-quadrant

    // staging geometry
    const int krb = wave * 16 + (lane >> 4) * 4;
    const int gr  = lane & 15;

    // tr_read per-lane geometry (verified in R5)
    const int c = lane & 15, g = lane >> 4;
    const int r = c >> 2, d = (c >> 1) & 1, h = c & 1;

    const unsigned ldsA0 = (unsigned)(uintptr_t)&sm.As[0];
    unsigned tbA[4], tbB[4];
    #pragma unroll
    for (int m = 0; m < 4; ++m)
        tbA[m] = ldsA0 + (8 * g + r) * 256
               + 16 * ((((wr >> 3) + 2 * m + d) ^ (2 * r))) + 8 * h;
    #pragma unroll
    for (int n = 0; n < 4; ++n)
        tbB[n] = ldsA0 + 16384 + (8 * g + r) * 256
               + 16 * ((((wc >> 3) + 2 * n + d) ^ (2 * r))) + 8 * h;

    const float* Ap = e1 + (size_t)b * D_ * N_ + tn;
    const float* Bp = e2 + (size_t)b * D_ * M_ + tc;

    f32x4 acc[4][4] = {};
    float4 flA[8], flB[8];

    load_tile(Ap, 0, krb, gr, flA);
    load_tile(Bp, 0, krb, gr, flB);

    #pragma unroll 1
    for (int ks = 0; ks < NSTEP; ++ks) {
        flush_tile((char*)sm.As, krb, gr, flA);
        flush_tile((char*)sm.Bs, krb, gr, flB);
        if (ks < NSTEP - 1) {   // prefetch next K-tile into regs; lands during compute
            load_tile(Ap, (ks + 1) * BK, krb, gr, flA);
            load_tile(Bp, (ks + 1) * BK, krb, gr, flB);
        }
        asm volatile("s_waitcnt lgkmcnt(0)" ::: "memory");  // ds_writes visible (no vmcnt drain)
        __builtin_amdgcn_s_barrier();

        #pragma unroll
        for (int kk = 0; kk < 2; ++kk) {
            s16x4 alo[4], ahi[4], blo[4], bhi[4];
            #pragma unroll
            for (int m = 0; m < 4; ++m) {
                asm volatile("ds_read_b64_tr_b16 %0, %1 offset:%2"
                             : "=v"(alo[m]) : "v"(tbA[m]), "n"(kk * 8192));
                asm volatile("ds_read_b64_tr_b16 %0, %1 offset:%2"
                             : "=v"(ahi[m]) : "v"(tbA[m]), "n"(kk * 8192 + 1024));
            }
            #pragma unroll
            for (int n = 0; n < 4; ++n) {
                asm volatile("ds_read_b64_tr_b16 %0, %1 offset:%2"
                             : "=v"(blo[n]) : "v"(tbB[n]), "n"(kk * 8192));
                asm volatile("ds_read_b64_tr_b16 %0, %1 offset:%2"
                             : "=v"(bhi[n]) : "v"(tbB[n]), "n"(kk * 8192 + 1024));
            }
            asm volatile("s_waitcnt lgkmcnt(0)" ::: "memory");
            __builtin_amdgcn_sched_barrier(0);
            bf16x8 af[4], bf[4];
            #pragma unroll
            for (int m = 0; m < 4; ++m)
                af[m] = __builtin_shufflevector(alo[m], ahi[m], 0, 1, 2, 3, 4, 5, 6, 7);
            #pragma unroll
            for (int n = 0; n < 4; ++n)
                bf[n] = __builtin_shufflevector(blo[n], bhi[n], 0, 1, 2, 3, 4, 5, 6, 7);
            __builtin_amdgcn_s_setprio(1);
            #pragma unroll
            for (int m = 0; m < 4; ++m)
                #pragma unroll
                for (int n = 0; n < 4; ++n)
                    acc[m][n] = __builtin_amdgcn_mfma_f32_16x16x32_bf16(
                        af[m], bf[n], acc[m][n], 0, 0, 0);
            __builtin_amdgcn_s_setprio(0);
        }
        // every wave's tr_reads were lgkm-drained before its MFMAs, so after
        // this barrier the buffer is safe to overwrite next iteration.
        __builtin_amdgcn_s_barrier();
    }

    // Max over this thread's 64 accumulator values.
    float tmax = acc[0][0][0];
    #pragma unroll
    for (int m = 0; m < 4; ++m)
        #pragma unroll
        for (int n = 0; n < 4; ++n)
            #pragma unroll
            for (int i = 0; i < 4; ++i)
                tmax = fmaxf(tmax, acc[m][n][i]);
    #pragma unroll
    for (int off2 = 32; off2; off2 >>= 1)
        tmax = fmaxf(tmax, __shfl_xor(tmax, off2));
    if (lane == 0) sm.red[wave] = tmax;
    __syncthreads();
    if (t == 0) {
        float m4 = fmaxf(fmaxf(sm.red[0], sm.red[1]), fmaxf(sm.red[2], sm.red[3]));
        atomicMax(reinterpret_cast<unsigned*>(out) + b, map_f(m4));
    }
}

__global__ void finalize_kernel(float* out) {
    const int i = threadIdx.x;
    unsigned u = reinterpret_cast<unsigned*>(out)[i];
    out[i] = __uint_as_float((u & 0x80000000u) ? (u ^ 0x80000000u) : ~u);
}

extern "C" void kernel_launch(void* const* d_in, const int* in_sizes, int n_in,
                              void* d_out, int out_size, void* d_ws, size_t ws_size,
                              hipStream_t stream) {
    const float* e1 = (const float*)d_in[0];
    const float* e2 = (const float*)d_in[1];
    float* out = (float*)d_out;

    hipMemsetAsync(d_out, 0, B_ * sizeof(float), stream);  // 0 == -inf under map_f

    fused_gemm_max_kernel<<<dim3(2048), 256, 0, stream>>>(e1, e2, out);
    finalize_kernel<<<1, B_, 0, stream>>>(out);
}

// Round 11
// 85.925 us; speedup vs baseline: 3.8584x; 3.8584x over previous
//
#include <hip/hip_runtime.h>
#include <hip/hip_bf16.h>

#define B_ 32
#define D_ 512
#define N_ 1024
#define M_ 1024
#define BM 128
#define BK 64
#define NSTEP (D_ / BK)   // 8

typedef __attribute__((ext_vector_type(8))) short bf16x8;
typedef __attribute__((ext_vector_type(4))) short s16x4;
typedef __attribute__((ext_vector_type(4))) float f32x4;
typedef __attribute__((ext_vector_type(4))) int   i32x4;
typedef unsigned short ushort_t;

__device__ __forceinline__ unsigned map_f(float f) {
    unsigned b = __float_as_uint(f);
    return (b & 0x80000000u) ? ~b : (b | 0x80000000u);
}

// ============================================================================
// Fused fp32->bf16 GEMM-max. SINGLE-buffered LDS (33KB). launch_bounds(256,3):
// 3 blocks/CU (12 waves) -- LDS would admit 4 but the ~160-reg footprint
// (64 acc AGPR + 64 staging VGPR + frags) only fits at 512/3=170 cap.
// R8's verified layout: LDS tile [k=64][j=128] bf16, row 256B = 16 granules;
// granule gr of row k at byte k*256 + 16*(gr ^ (2*(k&3))).  b128 writes
// (R8-verified), ds_read_b64_tr_b16 fragment reads (R5-verified correct).
// ============================================================================
struct __align__(16) GSmem {
    ushort_t As[BM * BK];   // 16 KB  @ 0
    ushort_t Bs[BM * BK];   // 16 KB  @ 16384
    float red[4];
};

// Load this thread's 4 granules (= 8 float4) of a [64][128] fp32 tile slice.
// krb = wave*16 + (lane>>4)*4 ; gr = lane&15. Per it: 16 lanes cover one full
// 512B row contiguously (two interleaved dwordx4 instrs).
__device__ __forceinline__ void load_tile(const float* __restrict__ p, int k0,
                                          int krb, int gr, float4* fl) {
    #pragma unroll
    for (int it = 0; it < 4; ++it) {
        const float* q = p + (size_t)(k0 + krb + it) * N_ + gr * 8;
        fl[2 * it]     = *reinterpret_cast<const float4*>(q);
        fl[2 * it + 1] = *reinterpret_cast<const float4*>(q + 4);
    }
}

// Convert + write this thread's 4 granules into one LDS tile (swizzled, b128).
__device__ __forceinline__ void flush_tile(char* lds, int krb, int gr, const float4* fl) {
    #pragma unroll
    for (int it = 0; it < 4; ++it) {
        const int k = krb + it;
        const float4& f0 = fl[2 * it];
        const float4& f1 = fl[2 * it + 1];
        __hip_bfloat162 h0 = __float22bfloat162_rn(make_float2(f0.x, f0.y));
        __hip_bfloat162 h1 = __float22bfloat162_rn(make_float2(f0.z, f0.w));
        __hip_bfloat162 h2 = __float22bfloat162_rn(make_float2(f1.x, f1.y));
        __hip_bfloat162 h3 = __float22bfloat162_rn(make_float2(f1.z, f1.w));
        i32x4 v = { *reinterpret_cast<const int*>(&h0), *reinterpret_cast<const int*>(&h1),
                    *reinterpret_cast<const int*>(&h2), *reinterpret_cast<const int*>(&h3) };
        *reinterpret_cast<i32x4*>(lds + k * 256 + 16 * (gr ^ (2 * (k & 3)))) = v;
    }
}

__global__ __launch_bounds__(256, 3)
void fused_gemm_max_kernel(const float* __restrict__ e1, const float* __restrict__ e2,
                           float* __restrict__ out) {
    __shared__ GSmem sm;
    const int wg  = blockIdx.x;
    const int swz = (wg & 7) * 256 + (wg >> 3);   // XCD swizzle (2048 % 8 == 0)
    const int b    = swz >> 6;
    const int tile = swz & 63;
    const int tn = (tile >> 3) * BM;
    const int tc = (tile & 7) * BM;

    const int t    = threadIdx.x;
    const int lane = t & 63;
    const int wave = t >> 6;
    const int wr   = (wave >> 1) * 64;   // A j-quadrant
    const int wc   = (wave & 1) * 64;    // B j-quadrant

    // staging geometry
    const int krb = wave * 16 + (lane >> 4) * 4;
    const int gr  = lane & 15;

    // tr_read per-lane geometry (verified in R5)
    const int c = lane & 15, g = lane >> 4;
    const int r = c >> 2, d = (c >> 1) & 1, h = c & 1;

    const unsigned ldsA0 = (unsigned)(uintptr_t)&sm.As[0];
    unsigned tbA[4], tbB[4];
    #pragma unroll
    for (int m = 0; m < 4; ++m)
        tbA[m] = ldsA0 + (8 * g + r) * 256
               + 16 * ((((wr >> 3) + 2 * m + d) ^ (2 * r))) + 8 * h;
    #pragma unroll
    for (int n = 0; n < 4; ++n)
        tbB[n] = ldsA0 + 16384 + (8 * g + r) * 256
               + 16 * ((((wc >> 3) + 2 * n + d) ^ (2 * r))) + 8 * h;

    const float* Ap = e1 + (size_t)b * D_ * N_ + tn;
    const float* Bp = e2 + (size_t)b * D_ * M_ + tc;

    f32x4 acc[4][4] = {};
    float4 flA[8], flB[8];

    load_tile(Ap, 0, krb, gr, flA);
    load_tile(Bp, 0, krb, gr, flB);

    #pragma unroll 1
    for (int ks = 0; ks < NSTEP; ++ks) {
        flush_tile((char*)sm.As, krb, gr, flA);
        flush_tile((char*)sm.Bs, krb, gr, flB);
        if (ks < NSTEP - 1) {   // prefetch next K-tile into regs; lands during compute
            load_tile(Ap, (ks + 1) * BK, krb, gr, flA);
            load_tile(Bp, (ks + 1) * BK, krb, gr, flB);
        }
        asm volatile("s_waitcnt lgkmcnt(0)" ::: "memory");  // ds_writes visible (no vmcnt drain)
        __builtin_amdgcn_s_barrier();

        #pragma unroll
        for (int kk = 0; kk < 2; ++kk) {
            s16x4 alo[4], ahi[4], blo[4], bhi[4];
            #pragma unroll
            for (int m = 0; m < 4; ++m) {
                asm volatile("ds_read_b64_tr_b16 %0, %1 offset:%2"
                             : "=v"(alo[m]) : "v"(tbA[m]), "n"(kk * 8192));
                asm volatile("ds_read_b64_tr_b16 %0, %1 offset:%2"
                             : "=v"(ahi[m]) : "v"(tbA[m]), "n"(kk * 8192 + 1024));
            }
            #pragma unroll
            for (int n = 0; n < 4; ++n) {
                asm volatile("ds_read_b64_tr_b16 %0, %1 offset:%2"
                             : "=v"(blo[n]) : "v"(tbB[n]), "n"(kk * 8192));
                asm volatile("ds_read_b64_tr_b16 %0, %1 offset:%2"
                             : "=v"(bhi[n]) : "v"(tbB[n]), "n"(kk * 8192 + 1024));
            }
            asm volatile("s_waitcnt lgkmcnt(0)" ::: "memory");
            __builtin_amdgcn_sched_barrier(0);
            bf16x8 af[4], bf[4];
            #pragma unroll
            for (int m = 0; m < 4; ++m)
                af[m] = __builtin_shufflevector(alo[m], ahi[m], 0, 1, 2, 3, 4, 5, 6, 7);
            #pragma unroll
            for (int n = 0; n < 4; ++n)
                bf[n] = __builtin_shufflevector(blo[n], bhi[n], 0, 1, 2, 3, 4, 5, 6, 7);
            __builtin_amdgcn_s_setprio(1);
            #pragma unroll
            for (int m = 0; m < 4; ++m)
                #pragma unroll
                for (int n = 0; n < 4; ++n)
                    acc[m][n] = __builtin_amdgcn_mfma_f32_16x16x32_bf16(
                        af[m], bf[n], acc[m][n], 0, 0, 0);
            __builtin_amdgcn_s_setprio(0);
        }
        // every wave's tr_reads were lgkm-drained before its MFMAs, so after
        // this barrier the buffer is safe to overwrite next iteration.
        __builtin_amdgcn_s_barrier();
    }

    // Max over this thread's 64 accumulator values.
    float tmax = acc[0][0][0];
    #pragma unroll
    for (int m = 0; m < 4; ++m)
        #pragma unroll
        for (int n = 0; n < 4; ++n)
            #pragma unroll
            for (int i = 0; i < 4; ++i)
                tmax = fmaxf(tmax, acc[m][n][i]);
    #pragma unroll
    for (int off2 = 32; off2; off2 >>= 1)
        tmax = fmaxf(tmax, __shfl_xor(tmax, off2));
    if (lane == 0) sm.red[wave] = tmax;
    __syncthreads();
    if (t == 0) {
        float m4 = fmaxf(fmaxf(sm.red[0], sm.red[1]), fmaxf(sm.red[2], sm.red[3]));
        atomicMax(reinterpret_cast<unsigned*>(out) + b, map_f(m4));
    }
}

__global__ void finalize_kernel(float* out) {
    const int i = threadIdx.x;
    unsigned u = reinterpret_cast<unsigned*>(out)[i];
    out[i] = __uint_as_float((u & 0x80000000u) ? (u ^ 0x80000000u) : ~u);
}

extern "C" void kernel_launch(void* const* d_in, const int* in_sizes, int n_in,
                              void* d_out, int out_size, void* d_ws, size_t ws_size,
                              hipStream_t stream) {
    const float* e1 = (const float*)d_in[0];
    const float* e2 = (const float*)d_in[1];
    float* out = (float*)d_out;

    hipMemsetAsync(d_out, 0, B_ * sizeof(float), stream);  // 0 == -inf under map_f

    fused_gemm_max_kernel<<<dim3(2048), 256, 0, stream>>>(e1, e2, out);
    finalize_kernel<<<1, B_, 0, stream>>>(out);
}

// Round 13
// 80.788 us; speedup vs baseline: 4.1037x; 1.0636x over previous
//
#include <hip/hip_runtime.h>
#include <hip/hip_bf16.h>

#define B_ 32
#define D_ 512
#define N_ 1024
#define M_ 1024
#define BM 128
#define BK 64
#define NSTEP (D_ / BK)   // 8

typedef __attribute__((ext_vector_type(8))) short bf16x8;
typedef __attribute__((ext_vector_type(4))) short s16x4;
typedef __attribute__((ext_vector_type(4))) float f32x4;
typedef __attribute__((ext_vector_type(4))) int   i32x4;
typedef unsigned short ushort_t;

__device__ __forceinline__ unsigned map_f(float f) {
    unsigned b = __float_as_uint(f);
    return (b & 0x80000000u) ? ~b : (b | 0x80000000u);
}

// ============================================================================
// Fused fp32->bf16 GEMM-max, double-buffered (R8 base, 66KB, 2 blocks/CU),
// with counted-lgkmcnt software pipeline (T4):
//   issue 32 tr_reads -> lgkmcnt(15) [>=17 done => kk0 batch complete] ->
//   MFMA kk0 -> flush+loads -> lgkmcnt(8) -> MFMA kk1 -> lgkmcnt(0) -> barrier.
// (lgkmcnt is a 4-bit field on gfx9: max 15 — learned R12.)
// Layout (R8-verified): LDS tile [k=64][j=128] bf16, granule gr of row k at
// byte k*256 + 16*(gr ^ (2*(k&3))); b128 writes; ds_read_b64_tr_b16 reads.
// ============================================================================
struct __align__(16) GSmem {
    ushort_t As[2][BM * BK];   // As[0]@0, As[1]@16384, Bs[0]@32768, Bs[1]@49152
    ushort_t Bs[2][BM * BK];
    float red[4];
};

// Load this thread's 4 granules (= 8 float4) of a [64][128] fp32 tile slice.
__device__ __forceinline__ void load_tile(const float* __restrict__ p, int k0,
                                          int krb, int gr, float4* fl) {
    #pragma unroll
    for (int it = 0; it < 4; ++it) {
        const float* q = p + (size_t)(k0 + krb + it) * N_ + gr * 8;
        fl[2 * it]     = *reinterpret_cast<const float4*>(q);
        fl[2 * it + 1] = *reinterpret_cast<const float4*>(q + 4);
    }
}

// Convert + write this thread's 4 granules into one LDS tile (swizzled, b128).
__device__ __forceinline__ void flush_tile(char* lds, int krb, int gr, const float4* fl) {
    #pragma unroll
    for (int it = 0; it < 4; ++it) {
        const int k = krb + it;
        const float4& f0 = fl[2 * it];
        const float4& f1 = fl[2 * it + 1];
        __hip_bfloat162 h0 = __float22bfloat162_rn(make_float2(f0.x, f0.y));
        __hip_bfloat162 h1 = __float22bfloat162_rn(make_float2(f0.z, f0.w));
        __hip_bfloat162 h2 = __float22bfloat162_rn(make_float2(f1.x, f1.y));
        __hip_bfloat162 h3 = __float22bfloat162_rn(make_float2(f1.z, f1.w));
        i32x4 v = { *reinterpret_cast<const int*>(&h0), *reinterpret_cast<const int*>(&h1),
                    *reinterpret_cast<const int*>(&h2), *reinterpret_cast<const int*>(&h3) };
        *reinterpret_cast<i32x4*>(lds + k * 256 + 16 * (gr ^ (2 * (k & 3)))) = v;
    }
}

__global__ __launch_bounds__(256, 2)
void fused_gemm_max_kernel(const float* __restrict__ e1, const float* __restrict__ e2,
                           float* __restrict__ out) {
    __shared__ GSmem sm;
    const int wg  = blockIdx.x;
    const int swz = (wg & 7) * 256 + (wg >> 3);   // XCD swizzle (2048 % 8 == 0)
    const int b    = swz >> 6;
    const int tile = swz & 63;
    const int tn = (tile >> 3) * BM;
    const int tc = (tile & 7) * BM;

    const int t    = threadIdx.x;
    const int lane = t & 63;
    const int wave = t >> 6;
    const int wr   = (wave >> 1) * 64;   // A j-quadrant
    const int wc   = (wave & 1) * 64;    // B j-quadrant

    // staging geometry
    const int krb = wave * 16 + (lane >> 4) * 4;
    const int gr  = lane & 15;

    // tr_read per-lane geometry (verified in R5)
    const int c = lane & 15, g = lane >> 4;
    const int r = c >> 2, d = (c >> 1) & 1, h = c & 1;

    const unsigned ldsA0 = (unsigned)(uintptr_t)&sm.As[0][0];
    unsigned tbA[4], tbB[4];
    #pragma unroll
    for (int m = 0; m < 4; ++m)
        tbA[m] = ldsA0 + (8 * g + r) * 256
               + 16 * ((((wr >> 3) + 2 * m + d) ^ (2 * r))) + 8 * h;
    #pragma unroll
    for (int n = 0; n < 4; ++n)
        tbB[n] = ldsA0 + 32768 + (8 * g + r) * 256
               + 16 * ((((wc >> 3) + 2 * n + d) ^ (2 * r))) + 8 * h;

    const float* Ap = e1 + (size_t)b * D_ * N_ + tn;
    const float* Bp = e2 + (size_t)b * D_ * M_ + tc;

    f32x4 acc[4][4] = {};
    float4 flA[8], flB[8];

    // Prologue: stage tile 0, then issue loads for tile 1.
    load_tile(Ap, 0, krb, gr, flA);
    load_tile(Bp, 0, krb, gr, flB);
    flush_tile((char*)sm.As[0], krb, gr, flA);
    flush_tile((char*)sm.Bs[0], krb, gr, flB);
    load_tile(Ap, BK, krb, gr, flA);
    load_tile(Bp, BK, krb, gr, flB);
    asm volatile("s_waitcnt lgkmcnt(0)" ::: "memory");
    __builtin_amdgcn_s_barrier();

    int cur = 0;
    #pragma unroll 1
    for (int ks = 0; ks < NSTEP; ++ks) {
        const unsigned off = (unsigned)cur * 16384u;

        // Issue ALL 32 tr_reads: kk0 batch (16) first, then kk1 batch (16).
        s16x4 alo[2][4], ahi[2][4], blo[2][4], bhi[2][4];
        #pragma unroll
        for (int kk = 0; kk < 2; ++kk) {
            #pragma unroll
            for (int m = 0; m < 4; ++m) {
                asm volatile("ds_read_b64_tr_b16 %0, %1 offset:%2"
                             : "=v"(alo[kk][m]) : "v"(tbA[m] + off), "n"(kk * 8192));
                asm volatile("ds_read_b64_tr_b16 %0, %1 offset:%2"
                             : "=v"(ahi[kk][m]) : "v"(tbA[m] + off), "n"(kk * 8192 + 1024));
            }
            #pragma unroll
            for (int n = 0; n < 4; ++n) {
                asm volatile("ds_read_b64_tr_b16 %0, %1 offset:%2"
                             : "=v"(blo[kk][n]) : "v"(tbB[n] + off), "n"(kk * 8192));
                asm volatile("ds_read_b64_tr_b16 %0, %1 offset:%2"
                             : "=v"(bhi[kk][n]) : "v"(tbB[n] + off), "n"(kk * 8192 + 1024));
            }
        }

        // kk0 fragments ready: lgkmcnt(15) => >=17 of 32 complete (in-order DS)
        // => all 16 kk0 reads done; 15 kk1 reads still hide under kk0 MFMAs.
        asm volatile("s_waitcnt lgkmcnt(15)" ::: "memory");
        __builtin_amdgcn_sched_barrier(0);
        {
            bf16x8 af[4], bf[4];
            #pragma unroll
            for (int m = 0; m < 4; ++m)
                af[m] = __builtin_shufflevector(alo[0][m], ahi[0][m], 0, 1, 2, 3, 4, 5, 6, 7);
            #pragma unroll
            for (int n = 0; n < 4; ++n)
                bf[n] = __builtin_shufflevector(blo[0][n], bhi[0][n], 0, 1, 2, 3, 4, 5, 6, 7);
            __builtin_amdgcn_s_setprio(1);
            #pragma unroll
            for (int m = 0; m < 4; ++m)
                #pragma unroll
                for (int n = 0; n < 4; ++n)
                    acc[m][n] = __builtin_amdgcn_mfma_f32_16x16x32_bf16(
                        af[m], bf[n], acc[m][n], 0, 0, 0);
            __builtin_amdgcn_s_setprio(0);
        }

        // Flush next tile into the other buffer; issue loads for ks+2.
        // (kk1's read latency + the write drain hide under kk0/kk1 MFMAs.)
        const bool has_flush = (ks < NSTEP - 1);
        if (has_flush) {
            flush_tile((char*)sm.As[cur ^ 1], krb, gr, flA);
            flush_tile((char*)sm.Bs[cur ^ 1], krb, gr, flB);
            if (ks < NSTEP - 2) {
                load_tile(Ap, (ks + 2) * BK, krb, gr, flA);
                load_tile(Bp, (ks + 2) * BK, krb, gr, flB);
            }
        }

        // kk1 fragments ready (the 8 ds_writes may still be outstanding).
        if (has_flush)
            asm volatile("s_waitcnt lgkmcnt(8)" ::: "memory");
        else
            asm volatile("s_waitcnt lgkmcnt(0)" ::: "memory");
        __builtin_amdgcn_sched_barrier(0);
        {
            bf16x8 af[4], bf[4];
            #pragma unroll
            for (int m = 0; m < 4; ++m)
                af[m] = __builtin_shufflevector(alo[1][m], ahi[1][m], 0, 1, 2, 3, 4, 5, 6, 7);
            #pragma unroll
            for (int n = 0; n < 4; ++n)
                bf[n] = __builtin_shufflevector(blo[1][n], bhi[1][n], 0, 1, 2, 3, 4, 5, 6, 7);
            __builtin_amdgcn_s_setprio(1);
            #pragma unroll
            for (int m = 0; m < 4; ++m)
                #pragma unroll
                for (int n = 0; n < 4; ++n)
                    acc[m][n] = __builtin_amdgcn_mfma_f32_16x16x32_bf16(
                        af[m], bf[n], acc[m][n], 0, 0, 0);
            __builtin_amdgcn_s_setprio(0);
        }

        asm volatile("s_waitcnt lgkmcnt(0)" ::: "memory");  // writes drained
        __builtin_amdgcn_s_barrier();
        cur ^= 1;
    }

    // Max over this thread's 64 accumulator values.
    float tmax = acc[0][0][0];
    #pragma unroll
    for (int m = 0; m < 4; ++m)
        #pragma unroll
        for (int n = 0; n < 4; ++n)
            #pragma unroll
            for (int i = 0; i < 4; ++i)
                tmax = fmaxf(tmax, acc[m][n][i]);
    #pragma unroll
    for (int off2 = 32; off2; off2 >>= 1)
        tmax = fmaxf(tmax, __shfl_xor(tmax, off2));
    if (lane == 0) sm.red[wave] = tmax;
    __syncthreads();
    if (t == 0) {
        float m4 = fmaxf(fmaxf(sm.red[0], sm.red[1]), fmaxf(sm.red[2], sm.red[3]));
        atomicMax(reinterpret_cast<unsigned*>(out) + b, map_f(m4));
    }
}

__global__ void finalize_kernel(float* out) {
    const int i = threadIdx.x;
    unsigned u = reinterpret_cast<unsigned*>(out)[i];
    out[i] = __uint_as_float((u & 0x80000000u) ? (u ^ 0x80000000u) : ~u);
}

extern "C" void kernel_launch(void* const* d_in, const int* in_sizes, int n_in,
                              void* d_out, int out_size, void* d_ws, size_t ws_size,
                              hipStream_t stream) {
    const float* e1 = (const float*)d_in[0];
    const float* e2 = (const float*)d_in[1];
    float* out = (float*)d_out;

    (void)hipMemsetAsync(d_out, 0, B_ * sizeof(float), stream);  // 0 == -inf under map_f

    fused_gemm_max_kernel<<<dim3(2048), 256, 0, stream>>>(e1, e2, out);
    finalize_kernel<<<1, B_, 0, stream>>>(out);
}

// Round 14
// 52.701 us; speedup vs baseline: 6.2909x; 1.5330x over previous
//
#include <hip/hip_runtime.h>
#include <hip/hip_bf16.h>

#define B_ 32
#define D_ 512
#define N_ 1024
#define M_ 1024
#define BT 256          // tile edge (both n and m)
#define BK 64
#define NSTEP (D_ / BK)   // 8

typedef __attribute__((ext_vector_type(8))) short bf16x8;
typedef __attribute__((ext_vector_type(4))) short s16x4;
typedef __attribute__((ext_vector_type(4))) float f32x4;
typedef __attribute__((ext_vector_type(4))) int   i32x4;
typedef unsigned short ushort_t;

__device__ __forceinline__ unsigned map_f(float f) {
    unsigned b = __float_as_uint(f);
    return (b & 0x80000000u) ? ~b : (b | 0x80000000u);
}

// ============================================================================
// Fused fp32->bf16 GEMM-max, 256x256 tile, 512 threads (8 waves, 2x4),
// per-wave 128x64 output. Double-buffered LDS (128KB), 1 block/CU.
// LDS tile [k=64][j=256] bf16, rows 512B = 32 granules of 16B; granule gr of
// row k at byte k*512 + 16*(gr ^ (2*(k&3)))  (R8 layout scaled 2x in j).
// Staging: ONE 32-reg buffer time-shared A/B (flush-A after kk0, flush-B
// after kk1) to stay under the 256-reg cap.  tr_read fragment path scaled:
// row stride 512, hi +2048, kk +16384.
// ============================================================================
struct __align__(16) GSmem {
    ushort_t As[2][BT * BK];   // 32KB each: As[0]@0, As[1]@32768
    ushort_t Bs[2][BT * BK];   // Bs[0]@65536, Bs[1]@98304
    float red[8];
};

// Load this thread's granule-column of a [64][256] fp32 tile: 4 rows x 8 cols.
// krb = (t>>5)*4, gr = t&31.  Per row: 32 lanes cover 1KB contiguously.
__device__ __forceinline__ void load_tile(const float* __restrict__ p, int k0,
                                          int krb, int gr, float4* fl) {
    #pragma unroll
    for (int it = 0; it < 4; ++it) {
        const float* q = p + (size_t)(k0 + krb + it) * N_ + gr * 8;
        fl[2 * it]     = *reinterpret_cast<const float4*>(q);
        fl[2 * it + 1] = *reinterpret_cast<const float4*>(q + 4);
    }
}

// Convert + write this thread's 4 granules into one LDS tile (swizzled, b128).
__device__ __forceinline__ void flush_tile(char* lds, int krb, int gr, const float4* fl) {
    #pragma unroll
    for (int it = 0; it < 4; ++it) {
        const int k = krb + it;
        const float4& f0 = fl[2 * it];
        const float4& f1 = fl[2 * it + 1];
        __hip_bfloat162 h0 = __float22bfloat162_rn(make_float2(f0.x, f0.y));
        __hip_bfloat162 h1 = __float22bfloat162_rn(make_float2(f0.z, f0.w));
        __hip_bfloat162 h2 = __float22bfloat162_rn(make_float2(f1.x, f1.y));
        __hip_bfloat162 h3 = __float22bfloat162_rn(make_float2(f1.z, f1.w));
        i32x4 v = { *reinterpret_cast<const int*>(&h0), *reinterpret_cast<const int*>(&h1),
                    *reinterpret_cast<const int*>(&h2), *reinterpret_cast<const int*>(&h3) };
        *reinterpret_cast<i32x4*>(lds + k * 512 + 16 * (gr ^ (2 * (k & 3)))) = v;
    }
}

__global__ __launch_bounds__(512, 2)
void fused_gemm_max_kernel(const float* __restrict__ e1, const float* __restrict__ e2,
                           float* __restrict__ out) {
    __shared__ GSmem sm;
    const int wg  = blockIdx.x;
    const int swz = (wg & 7) * 64 + (wg >> 3);   // XCD swizzle (512 % 8 == 0)
    const int b    = swz >> 4;                   // 16 tiles per batch (4x4)
    const int tile = swz & 15;
    const int tn = (tile >> 2) * BT;             // e1 column-panel
    const int tc = (tile & 3) * BT;              // e2 column-panel

    const int t    = threadIdx.x;
    const int lane = t & 63;
    const int wave = t >> 6;                     // 0..7
    const int wrow = (wave >> 2) * 128;          // A j-offset (2 groups)
    const int wcol = (wave & 3) * 64;            // B j-offset (4 groups)

    // staging geometry: 512 threads cover [64][256]: 16 row-groups x 32 granules
    const int krb = (t >> 5) * 4;
    const int gr  = t & 31;

    // tr_read per-lane geometry (R5-verified pattern, stride scaled to 512B)
    const int c = lane & 15, g = lane >> 4;
    const int r = c >> 2, d = (c >> 1) & 1, h = c & 1;

    unsigned tbA[8], tbB[4];
    #pragma unroll
    for (int m = 0; m < 8; ++m)
        tbA[m] = (unsigned)((8 * g + r) * 512
               + 16 * ((((wrow >> 3) + 2 * m + d) ^ (2 * r))) + 8 * h);
    #pragma unroll
    for (int n = 0; n < 4; ++n)
        tbB[n] = (unsigned)(65536 + (8 * g + r) * 512
               + 16 * ((((wcol >> 3) + 2 * n + d) ^ (2 * r))) + 8 * h);
    const unsigned ldsbase = (unsigned)(uintptr_t)&sm.As[0][0];

    const float* Ap = e1 + (size_t)b * D_ * N_ + tn;
    const float* Bp = e2 + (size_t)b * D_ * M_ + tc;

    f32x4 acc[8][4] = {};
    float4 fl[8];                                // ONE staging buffer, time-shared

    // Prologue (serial, once): A0 -> LDS0, B0 -> LDS0, then issue A1 loads.
    load_tile(Ap, 0, krb, gr, fl);
    flush_tile((char*)sm.As[0], krb, gr, fl);
    load_tile(Bp, 0, krb, gr, fl);
    flush_tile((char*)sm.Bs[0], krb, gr, fl);
    load_tile(Ap, BK, krb, gr, fl);
    asm volatile("s_waitcnt lgkmcnt(0)" ::: "memory");
    __builtin_amdgcn_s_barrier();

    int cur = 0;
    #pragma unroll 1
    for (int ks = 0; ks < NSTEP; ++ks) {
        const unsigned off = ldsbase + (unsigned)cur * 32768u;
        const bool has_next = (ks < NSTEP - 1);

        #pragma unroll
        for (int kk = 0; kk < 2; ++kk) {
            s16x4 alo[8], ahi[8], blo[4], bhi[4];
            #pragma unroll
            for (int m = 0; m < 8; ++m) {
                asm volatile("ds_read_b64_tr_b16 %0, %1 offset:%2"
                             : "=v"(alo[m]) : "v"(tbA[m] + off), "n"(kk * 16384));
                asm volatile("ds_read_b64_tr_b16 %0, %1 offset:%2"
                             : "=v"(ahi[m]) : "v"(tbA[m] + off), "n"(kk * 16384 + 2048));
            }
            #pragma unroll
            for (int n = 0; n < 4; ++n) {
                asm volatile("ds_read_b64_tr_b16 %0, %1 offset:%2"
                             : "=v"(blo[n]) : "v"(tbB[n] + off), "n"(kk * 16384));
                asm volatile("ds_read_b64_tr_b16 %0, %1 offset:%2"
                             : "=v"(bhi[n]) : "v"(tbB[n] + off), "n"(kk * 16384 + 2048));
            }
            asm volatile("s_waitcnt lgkmcnt(0)" ::: "memory");
            __builtin_amdgcn_sched_barrier(0);
            bf16x8 af[8], bf[4];
            #pragma unroll
            for (int m = 0; m < 8; ++m)
                af[m] = __builtin_shufflevector(alo[m], ahi[m], 0, 1, 2, 3, 4, 5, 6, 7);
            #pragma unroll
            for (int n = 0; n < 4; ++n)
                bf[n] = __builtin_shufflevector(blo[n], bhi[n], 0, 1, 2, 3, 4, 5, 6, 7);
            __builtin_amdgcn_s_setprio(1);
            #pragma unroll
            for (int m = 0; m < 8; ++m)
                #pragma unroll
                for (int n = 0; n < 4; ++n)
                    acc[m][n] = __builtin_amdgcn_mfma_f32_16x16x32_bf16(
                        af[m], bf[n], acc[m][n], 0, 0, 0);
            __builtin_amdgcn_s_setprio(0);

            // Time-shared staging between the two MFMA clusters:
            if (kk == 0 && has_next) {
                flush_tile((char*)sm.As[cur ^ 1], krb, gr, fl);  // A(ks+1) -> LDS
                load_tile(Bp, (ks + 1) * BK, krb, gr, fl);       // issue B(ks+1) loads
            }
        }
        if (has_next) {
            flush_tile((char*)sm.Bs[cur ^ 1], krb, gr, fl);      // B(ks+1) -> LDS
            if (ks < NSTEP - 2)
                load_tile(Ap, (ks + 2) * BK, krb, gr, fl);       // issue A(ks+2) loads
        }
        asm volatile("s_waitcnt lgkmcnt(0)" ::: "memory");       // ds_writes drained
        __builtin_amdgcn_s_barrier();
        cur ^= 1;
    }

    // Max over this thread's 128 accumulator values.
    float tmax = acc[0][0][0];
    #pragma unroll
    for (int m = 0; m < 8; ++m)
        #pragma unroll
        for (int n = 0; n < 4; ++n)
            #pragma unroll
            for (int i = 0; i < 4; ++i)
                tmax = fmaxf(tmax, acc[m][n][i]);
    #pragma unroll
    for (int off2 = 32; off2; off2 >>= 1)
        tmax = fmaxf(tmax, __shfl_xor(tmax, off2));
    if (lane == 0) sm.red[wave] = tmax;
    __syncthreads();
    if (t == 0) {
        float m8 = sm.red[0];
        #pragma unroll
        for (int w = 1; w < 8; ++w) m8 = fmaxf(m8, sm.red[w]);
        atomicMax(reinterpret_cast<unsigned*>(out) + b, map_f(m8));
    }
}

__global__ void finalize_kernel(float* out) {
    const int i = threadIdx.x;
    unsigned u = reinterpret_cast<unsigned*>(out)[i];
    out[i] = __uint_as_float((u & 0x80000000u) ? (u ^ 0x80000000u) : ~u);
}

extern "C" void kernel_launch(void* const* d_in, const int* in_sizes, int n_in,
                              void* d_out, int out_size, void* d_ws, size_t ws_size,
                              hipStream_t stream) {
    const float* e1 = (const float*)d_in[0];
    const float* e2 = (const float*)d_in[1];
    float* out = (float*)d_out;

    (void)hipMemsetAsync(d_out, 0, B_ * sizeof(float), stream);  // 0 == -inf under map_f

    fused_gemm_max_kernel<<<dim3(512), 512, 0, stream>>>(e1, e2, out);
    finalize_kernel<<<1, B_, 0, stream>>>(out);
}